// Round 1
// baseline (27.429 us; speedup 1.0000x reference)
//
#include <hip/hip_runtime.h>
#include <math.h>

#define SEQ 8192
#define HID 4096

// ---------------------------------------------------------------------------
// Kernel 1: energies[r] = dot(encoder_outputs[r, :], hidden[:])
// One 64-lane wave per row. 16x float4 loads per lane (fully coalesced:
// 64 lanes x 16B = 1 KiB per instruction), then shfl_xor wave reduction.
// ---------------------------------------------------------------------------
__global__ __launch_bounds__(256) void matvec_kernel(
    const float* __restrict__ hidden,     // [HID]
    const float* __restrict__ eo,         // [SEQ, HID]
    float* __restrict__ energies)         // [SEQ]
{
    const int gwave = (blockIdx.x * blockDim.x + threadIdx.x) >> 6;  // row id
    const int lane  = threadIdx.x & 63;
    if (gwave >= SEQ) return;

    const float4* __restrict__ row = (const float4*)(eo + (size_t)gwave * HID);
    const float4* __restrict__ hv  = (const float4*)hidden;

    float acc = 0.0f;
#pragma unroll
    for (int k = 0; k < (HID / 4) / 64; ++k) {    // 16 iterations
        float4 a = row[k * 64 + lane];
        float4 b = hv [k * 64 + lane];            // hidden: L1/L2 resident
        acc += a.x * b.x + a.y * b.y + a.z * b.z + a.w * b.w;
    }

    // 64-lane butterfly reduction
#pragma unroll
    for (int off = 32; off > 0; off >>= 1)
        acc += __shfl_xor(acc, off, 64);

    if (lane == 0) energies[gwave] = acc;
}

// ---------------------------------------------------------------------------
// Kernel 2: out = softmax(energies) over SEQ elements. Single block.
// 256 threads x 32 values each, held in registers between passes.
// ---------------------------------------------------------------------------
__global__ __launch_bounds__(256) void softmax_kernel(
    const float* __restrict__ energies,   // [SEQ]
    float* __restrict__ out)              // [SEQ]
{
    __shared__ float red[8];
    const int tid  = threadIdx.x;
    const int wid  = tid >> 6;            // wave id 0..3
    const int lane = tid & 63;

    float v[32];
    float m = -INFINITY;
#pragma unroll
    for (int i = 0; i < 32; ++i) {
        v[i] = energies[i * 256 + tid];   // coalesced strided load
        m = fmaxf(m, v[i]);
    }
    // wave-level max
#pragma unroll
    for (int off = 32; off > 0; off >>= 1)
        m = fmaxf(m, __shfl_xor(m, off, 64));
    if (lane == 0) red[wid] = m;
    __syncthreads();
    const float gmax = fmaxf(fmaxf(red[0], red[1]), fmaxf(red[2], red[3]));

    float s = 0.0f;
#pragma unroll
    for (int i = 0; i < 32; ++i) {
        v[i] = __expf(v[i] - gmax);
        s += v[i];
    }
    // wave-level sum
#pragma unroll
    for (int off = 32; off > 0; off >>= 1)
        s += __shfl_xor(s, off, 64);
    if (lane == 0) red[4 + wid] = s;      // distinct slots: no hazard w/ red[0..3] reads
    __syncthreads();
    const float total = (red[4] + red[5]) + (red[6] + red[7]);
    const float inv = 1.0f / total;

#pragma unroll
    for (int i = 0; i < 32; ++i)
        out[i * 256 + tid] = v[i] * inv;
}

extern "C" void kernel_launch(void* const* d_in, const int* in_sizes, int n_in,
                              void* d_out, int out_size, void* d_ws, size_t ws_size,
                              hipStream_t stream) {
    const float* hidden = (const float*)d_in[0];   // [1, 4096] fp32
    const float* eo     = (const float*)d_in[1];   // [8192, 4096] fp32
    float* out          = (float*)d_out;           // [1, 1, 8192] fp32
    float* energies     = (float*)d_ws;            // 8192 floats scratch

    // 8192 rows, 1 wave (64 lanes) per row, 4 waves per 256-thread block
    matvec_kernel<<<SEQ / 4, 256, 0, stream>>>(hidden, eo, energies);
    softmax_kernel<<<1, 256, 0, stream>>>(energies, out);
}